// Round 2
// baseline (177.429 us; speedup 1.0000x reference)
//
#include <hip/hip_runtime.h>
#include <hip/hip_bf16.h>

typedef __bf16 bf16_t;
typedef __attribute__((ext_vector_type(4))) float f32x4;
typedef __attribute__((ext_vector_type(8))) __bf16 bf16x8;
typedef __attribute__((ext_vector_type(4))) __bf16 bf16x4;
typedef __attribute__((ext_vector_type(2))) __bf16 bf16x2;

#define NQ    1024
#define DIM   384
#define NHEAD 8
#define HDIM  48
#define HALFD 24
#define NLVL  4
#define NSZ   7
#define NKEY  196
#define NFREQ 8
#define TOTAL 5440   // 64*64 + 32*32 + 16*16 + 8*8

// ---------------------------------------------------------------------------
// Generic NT GEMM: C[M,N] = A[M,K] * B[N,K]^T   (A,B fp32 in; bf16 MFMA)
// EPI: 0 = fp32 C, 1 = fp32 C + residual, 2 = bf16 C
// Tiles: 128x128, BK=32, 4 waves each computing a 64x64 sub-tile (4x4 frags).
// ---------------------------------------------------------------------------
template<int EPI>
__global__ __launch_bounds__(256) void gemm_nt(
    const float* __restrict__ A, const float* __restrict__ Bw,
    void* __restrict__ Cp, const float* __restrict__ resid,
    int M, int Nout, int K)
{
    __shared__ bf16_t As[128][40];
    __shared__ bf16_t Bs[128][40];
    const int tid  = threadIdx.x;
    const int bm   = blockIdx.y, bn = blockIdx.x;
    const int wave = tid >> 6, lane = tid & 63;
    const int wr   = wave >> 1, wc = wave & 1;
    const int fr   = lane & 15, fk = (lane >> 4) << 3;

    f32x4 acc[4][4];
#pragma unroll
    for (int i = 0; i < 4; ++i)
#pragma unroll
        for (int j = 0; j < 4; ++j) acc[i][j] = (f32x4){0.f, 0.f, 0.f, 0.f};

    const float* Ab = A  + (size_t)bm * 128 * K;
    const float* Bb = Bw + (size_t)bn * 128 * K;

    for (int kt = 0; kt < K; kt += 32) {
        __syncthreads();
#pragma unroll
        for (int i = 0; i < 4; ++i) {
            int idx = tid + i * 256;
            int r = idx >> 3, c4 = (idx & 7) << 2;
            float4 va = *(const float4*)(Ab + (size_t)r * K + kt + c4);
            bf16x4 pa = { (bf16_t)va.x, (bf16_t)va.y, (bf16_t)va.z, (bf16_t)va.w };
            *(bf16x4*)(&As[r][c4]) = pa;
            float4 vb = *(const float4*)(Bb + (size_t)r * K + kt + c4);
            bf16x4 pb = { (bf16_t)vb.x, (bf16_t)vb.y, (bf16_t)vb.z, (bf16_t)vb.w };
            *(bf16x4*)(&Bs[r][c4]) = pb;
        }
        __syncthreads();
        bf16x8 af[4], bfr[4];
#pragma unroll
        for (int mi = 0; mi < 4; ++mi)
            af[mi] = *(const bf16x8*)(&As[wr * 64 + mi * 16 + fr][fk]);
#pragma unroll
        for (int ni = 0; ni < 4; ++ni)
            bfr[ni] = *(const bf16x8*)(&Bs[wc * 64 + ni * 16 + fr][fk]);
#pragma unroll
        for (int mi = 0; mi < 4; ++mi)
#pragma unroll
            for (int ni = 0; ni < 4; ++ni)
                acc[mi][ni] = __builtin_amdgcn_mfma_f32_16x16x32_bf16(
                    af[mi], bfr[ni], acc[mi][ni], 0, 0, 0);
    }

    const int r0 = (lane >> 4) << 2;
#pragma unroll
    for (int mi = 0; mi < 4; ++mi) {
#pragma unroll
        for (int ni = 0; ni < 4; ++ni) {
#pragma unroll
            for (int e = 0; e < 4; ++e) {
                int row = bm * 128 + wr * 64 + mi * 16 + r0 + e;
                int col = bn * 128 + wc * 64 + ni * 16 + fr;
                float v = acc[mi][ni][e];
                if (EPI == 2) {
                    ((bf16_t*)Cp)[(size_t)row * Nout + col] = (bf16_t)v;
                } else {
                    if (EPI == 1) v += resid[(size_t)row * Nout + col];
                    ((float*)Cp)[(size_t)row * Nout + col] = v;
                }
            }
        }
    }
}

// ---------------------------------------------------------------------------
// LayerNorm: one wave per row of 384
// ---------------------------------------------------------------------------
__global__ __launch_bounds__(64) void ln_kernel(
    const float* __restrict__ q, const float* __restrict__ w,
    const float* __restrict__ b, float* __restrict__ xout)
{
    const int n = blockIdx.x, lane = threadIdx.x;
    const float* row = q + (size_t)n * DIM;
    float v[6], s = 0.f, s2 = 0.f;
#pragma unroll
    for (int i = 0; i < 6; ++i) {
        v[i] = row[lane + i * 64];
        s += v[i]; s2 += v[i] * v[i];
    }
#pragma unroll
    for (int m = 32; m; m >>= 1) { s += __shfl_xor(s, m); s2 += __shfl_xor(s2, m); }
    float mu  = s * (1.f / DIM);
    float var = s2 * (1.f / DIM) - mu * mu;
    float rs  = rsqrtf(var + 1e-5f);
#pragma unroll
    for (int i = 0; i < 6; ++i) {
        int d = lane + i * 64;
        xout[(size_t)n * DIM + d] = (v[i] - mu) * rs * w[d] + b[d];
    }
}

// ---------------------------------------------------------------------------
// Pre-rotate the k-half of the kv map in place.
// Key RoPE angle depends only on the key's own (i, j, level) -> query-indep.
// One thread per (row, head, freq-pair): 2 bf16 loads, sincos, 2 bf16 stores.
// ---------------------------------------------------------------------------
__global__ __launch_bounds__(256) void rope_k_kernel(bf16_t* __restrict__ kvm, int Mkv)
{
    int task = blockIdx.x * 256 + threadIdx.x;
    if (task >= Mkv * (NHEAD * HALFD)) return;
    int row = task / (NHEAD * HALFD);
    int p   = task - row * (NHEAD * HALFD);
    int h = p / HALFD, d = p - h * HALFD;

    int rr = row % TOTAL;   // position within one batch's stacked map
    int l, i, j;
    if (rr < 4096)      { l = 0; i = rr >> 6;              j = rr & 63; }
    else if (rr < 5120) { l = 1; int t = rr - 4096; i = t >> 5; j = t & 31; }
    else if (rr < 5376) { l = 2; int t = rr - 5120; i = t >> 4; j = t & 15; }
    else                { l = 3; int t = rr - 5376; i = t >> 3; j = t & 7;  }

    float coord, freq;
    if (d < 8)       { coord = (float)i; freq = powf(10.0f, -(float)d * 0.125f); }
    else if (d < 16) { coord = (float)j; freq = powf(10.0f, -(float)(d - 8) * 0.125f); }
    else             { coord = (float)l; freq = powf(10.0f,  (float)(d - 16) * 0.125f); }
    float s, c;
    __sincosf(coord * freq, &s, &c);

    bf16_t* base = kvm + (size_t)row * (2 * DIM) + h * HDIM + d;
    float x1 = (float)base[0];
    float x2 = (float)base[HALFD];
    base[0]     = (bf16_t)(x1 * c - x2 * s);
    base[HALFD] = (bf16_t)(x1 * s + x2 * c);
}

// ---------------------------------------------------------------------------
// Attention: one block (256 threads) per query; k already RoPE'd in kvm.
// ---------------------------------------------------------------------------
__global__ __launch_bounds__(256) void attn_kernel(
    const float* __restrict__ qproj,   // (N,384) pre-RoPE
    const int*   __restrict__ pos,     // (N,4) b,i,j,l
    const bf16_t* __restrict__ kvm,    // (B*total, 768) bf16, k pre-rotated
    float* __restrict__ attn_out)      // (N,384)
{
    __shared__ float qs[DIM];
    __shared__ float sc[NHEAD * NKEY];
    __shared__ int   flatL[NKEY], validL[NKEY];

    const int n = blockIdx.x, tid = threadIdx.x;
    const int b  = pos[n * 4 + 0];
    const int qi = pos[n * 4 + 1];
    const int qj = pos[n * 4 + 2];
    const int ql = pos[n * 4 + 3];

    const float Hq = (float)(64 >> ql);   // H == W at every level

    // q RoPE -> qs
    if (tid < NHEAD * HALFD) {
        int h = tid / HALFD, d = tid - h * HALFD;
        float coord, freq;
        if (d < 8)       { coord = (float)qi; freq = powf(10.0f, -(float)d * 0.125f); }
        else if (d < 16) { coord = (float)qj; freq = powf(10.0f, -(float)(d - 8) * 0.125f); }
        else             { coord = (float)ql; freq = powf(10.0f,  (float)(d - 16) * 0.125f); }
        float s, c;
        __sincosf(coord * freq, &s, &c);
        float x1 = qproj[(size_t)n * DIM + h * HDIM + d];
        float x2 = qproj[(size_t)n * DIM + h * HDIM + HALFD + d];
        qs[h * HDIM + d]         = x1 * c - x2 * s;
        qs[h * HDIM + HALFD + d] = x1 * s + x2 * c;
    }

    // per-key geometry
    if (tid < NKEY) {
        int kk = tid;
        int l = kk / 49;
        int rem = kk - l * 49;
        int a = rem / 7, bb = rem - a * 7;
        int Hl = 64 >> l;
        int off = (l == 0) ? 0 : (l == 1) ? 4096 : (l == 2) ? 5120 : 5376;
        float cif = floorf(((float)qi + 0.5f) * (float)Hl / Hq);
        float cjf = floorf(((float)qj + 0.5f) * (float)Hl / Hq);
        int ii = (int)cif + (a - 3);
        int jj = (int)cjf + (bb - 3);
        int vi = (ii >= 0) && (ii < Hl);
        int vj = (jj >= 0) && (jj < Hl);
        int iic = min(max(ii, 0), Hl - 1);
        int jjc = min(max(jj, 0), Hl - 1);
        flatL[kk]  = off + iic * Hl + jjc;
        validL[kk] = vi && vj;
    }
    __syncthreads();

    const size_t bbase = (size_t)b * TOTAL;

    // scores: 8 heads x 196 keys (k is pre-rotated)
    for (int idx = tid; idx < NHEAD * NKEY; idx += 256) {
        int h = idx / NKEY, kk = idx - h * NKEY;
        const bf16_t* krow = kvm + (bbase + (size_t)flatL[kk]) * (2 * DIM) + h * HDIM;
        bf16x8 kv[6];
#pragma unroll
        for (int i = 0; i < 6; ++i) kv[i] = *(const bf16x8*)(krow + i * 8);
        float dot = 0.f;
#pragma unroll
        for (int i = 0; i < 6; ++i)
#pragma unroll
            for (int e = 0; e < 8; ++e)
                dot += (float)kv[i][e] * qs[h * HDIM + i * 8 + e];
        float score = dot * 0.14433756729740643f;  // 1/sqrt(48)
        if (!validL[kk]) score = -1e9f;
        sc[h * NKEY + kk] = score;
    }
    __syncthreads();

    // softmax: head h handled by threads [h*32, h*32+32)
    {
        int h = tid >> 5, lg = tid & 31;
        float mx = -1e30f;
        for (int j = lg; j < NKEY; j += 32) mx = fmaxf(mx, sc[h * NKEY + j]);
#pragma unroll
        for (int m = 16; m; m >>= 1) mx = fmaxf(mx, __shfl_xor(mx, m));
        float sum = 0.f;
        for (int j = lg; j < NKEY; j += 32) {
            float e = __expf(sc[h * NKEY + j] - mx);
            sc[h * NKEY + j] = e; sum += e;
        }
#pragma unroll
        for (int m = 16; m; m >>= 1) sum += __shfl_xor(sum, m);
        float inv = 1.f / sum;
        for (int j = lg; j < NKEY; j += 32) sc[h * NKEY + j] *= inv;
    }
    __syncthreads();

    // V accumulation: 192 threads x 2 dims
    if (tid < 192) {
        int h = tid / 24;
        float a0 = 0.f, a1 = 0.f;
#pragma unroll 4
        for (int kk = 0; kk < NKEY; ++kk) {
            float w = sc[h * NKEY + kk];
            const bf16_t* vr = kvm + (bbase + (size_t)flatL[kk]) * (2 * DIM) + DIM + 2 * tid;
            bf16x2 vv = *(const bf16x2*)vr;
            a0 += w * (float)vv[0];
            a1 += w * (float)vv[1];
        }
        attn_out[(size_t)n * DIM + 2 * tid]     = a0;
        attn_out[(size_t)n * DIM + 2 * tid + 1] = a1;
    }
}

// ---------------------------------------------------------------------------
extern "C" void kernel_launch(void* const* d_in, const int* in_sizes, int n_in,
                              void* d_out, int out_size, void* d_ws, size_t ws_size,
                              hipStream_t stream)
{
    const float* query  = (const float*)d_in[0];
    const int*   pos    = (const int*)d_in[1];
    const float* fmaps  = (const float*)d_in[3];
    const float* nw     = (const float*)d_in[5];
    const float* nb     = (const float*)d_in[6];
    const float* wq     = (const float*)d_in[7];
    const float* wkv    = (const float*)d_in[8];
    const float* wout   = (const float*)d_in[9];
    float* out = (float*)d_out;

    const int Mkv = in_sizes[3] / DIM;  // B*total = 21760

    char* w = (char*)d_ws;
    float* x_ln   = (float*)w;  w += ((size_t)NQ * DIM * 4 + 255) / 256 * 256;
    float* qproj  = (float*)w;  w += ((size_t)NQ * DIM * 4 + 255) / 256 * 256;
    float* attn_o = (float*)w;  w += ((size_t)NQ * DIM * 4 + 255) / 256 * 256;
    bf16_t* kvm   = (bf16_t*)w; // Mkv * 768 * 2 bytes

    ln_kernel<<<NQ, 64, 0, stream>>>(query, nw, nb, x_ln);
    gemm_nt<0><<<dim3(DIM / 128, NQ / 128), 256, 0, stream>>>(
        x_ln, wq, (void*)qproj, nullptr, NQ, DIM, DIM);
    gemm_nt<2><<<dim3((2 * DIM) / 128, Mkv / 128), 256, 0, stream>>>(
        fmaps, wkv, (void*)kvm, nullptr, Mkv, 2 * DIM, DIM);
    {
        int tasks = Mkv * (NHEAD * HALFD);
        rope_k_kernel<<<(tasks + 255) / 256, 256, 0, stream>>>(kvm, Mkv);
    }
    attn_kernel<<<NQ, 256, 0, stream>>>(qproj, pos, kvm, attn_o);
    gemm_nt<1><<<dim3(DIM / 128, NQ / 128), 256, 0, stream>>>(
        attn_o, wout, (void*)out, query, NQ, DIM, DIM);
}

// Round 3
// 117.011 us; speedup vs baseline: 1.5163x; 1.5163x over previous
//
#include <hip/hip_runtime.h>
#include <hip/hip_bf16.h>

typedef __bf16 bf16_t;
typedef __attribute__((ext_vector_type(4))) float f32x4;
typedef __attribute__((ext_vector_type(8))) __bf16 bf16x8;
typedef __attribute__((ext_vector_type(4))) __bf16 bf16x4;
typedef __attribute__((ext_vector_type(2))) __bf16 bf16x2;

#define NQ    1024
#define DIM   384
#define NHEAD 8
#define HDIM  48
#define HALFD 24
#define NLVL  4
#define NKEY  196
#define TOTAL 5440   // 64*64 + 32*32 + 16*16 + 8*8

// ---------------------------------------------------------------------------
// Generic NT GEMM: C[M,N] = A[M,K] * B[N,K]^T   (A,B fp32 in; bf16 MFMA)
// EPI: 0 = fp32 C, 1 = fp32 C + residual, 2 = bf16 C
// BT: square tile (128 -> 4 waves x 64x64; 64 -> 4 waves x 32x32)
// Bijective XCD swizzle (m204): contiguous block chunks per XCD for L2 reuse.
// ---------------------------------------------------------------------------
template<int EPI, int BT>
__global__ __launch_bounds__(256) void gemm_nt(
    const float* __restrict__ A, const float* __restrict__ Bw,
    void* __restrict__ Cp, const float* __restrict__ resid,
    int M, int Nout, int K)
{
    constexpr int FRG = BT / 32;   // fragments per wave dim
    constexpr int WT  = BT / 2;    // wave tile
    __shared__ bf16_t As[BT][40];
    __shared__ bf16_t Bs[BT][40];
    const int tid  = threadIdx.x;

    // XCD-aware bijective remap of linear block id
    const int bid = blockIdx.y * gridDim.x + blockIdx.x;
    const int nwg = gridDim.x * gridDim.y;
    const int qq = nwg >> 3, rr8 = nwg & 7;
    const int xcd = bid & 7, loc = bid >> 3;
    const int swz = (xcd < rr8 ? xcd * (qq + 1) : rr8 * (qq + 1) + (xcd - rr8) * qq) + loc;
    const int bm = swz / gridDim.x, bn = swz % gridDim.x;

    const int wave = tid >> 6, lane = tid & 63;
    const int wr   = wave >> 1, wc = wave & 1;
    const int fr   = lane & 15, fk = (lane >> 4) << 3;

    f32x4 acc[FRG][FRG];
#pragma unroll
    for (int i = 0; i < FRG; ++i)
#pragma unroll
        for (int j = 0; j < FRG; ++j) acc[i][j] = (f32x4){0.f, 0.f, 0.f, 0.f};

    const float* Ab = A  + (size_t)bm * BT * K;
    const float* Bb = Bw + (size_t)bn * BT * K;

    for (int kt = 0; kt < K; kt += 32) {
        __syncthreads();
#pragma unroll
        for (int i = 0; i < BT / 32; ++i) {
            int idx = tid + i * 256;
            int r = idx >> 3, c4 = (idx & 7) << 2;
            float4 va = *(const float4*)(Ab + (size_t)r * K + kt + c4);
            bf16x4 pa = { (bf16_t)va.x, (bf16_t)va.y, (bf16_t)va.z, (bf16_t)va.w };
            *(bf16x4*)(&As[r][c4]) = pa;
            float4 vb = *(const float4*)(Bb + (size_t)r * K + kt + c4);
            bf16x4 pb = { (bf16_t)vb.x, (bf16_t)vb.y, (bf16_t)vb.z, (bf16_t)vb.w };
            *(bf16x4*)(&Bs[r][c4]) = pb;
        }
        __syncthreads();
        bf16x8 af[FRG], bfr[FRG];
#pragma unroll
        for (int mi = 0; mi < FRG; ++mi)
            af[mi] = *(const bf16x8*)(&As[wr * WT + mi * 16 + fr][fk]);
#pragma unroll
        for (int ni = 0; ni < FRG; ++ni)
            bfr[ni] = *(const bf16x8*)(&Bs[wc * WT + ni * 16 + fr][fk]);
#pragma unroll
        for (int mi = 0; mi < FRG; ++mi)
#pragma unroll
            for (int ni = 0; ni < FRG; ++ni)
                acc[mi][ni] = __builtin_amdgcn_mfma_f32_16x16x32_bf16(
                    af[mi], bfr[ni], acc[mi][ni], 0, 0, 0);
    }

    const int r0 = (lane >> 4) << 2;
#pragma unroll
    for (int mi = 0; mi < FRG; ++mi) {
#pragma unroll
        for (int ni = 0; ni < FRG; ++ni) {
#pragma unroll
            for (int e = 0; e < 4; ++e) {
                int row = bm * BT + wr * WT + mi * 16 + r0 + e;
                int col = bn * BT + wc * WT + ni * 16 + fr;
                float v = acc[mi][ni][e];
                if (EPI == 2) {
                    ((bf16_t*)Cp)[(size_t)row * Nout + col] = (bf16_t)v;
                } else {
                    if (EPI == 1) v += resid[(size_t)row * Nout + col];
                    ((float*)Cp)[(size_t)row * Nout + col] = v;
                }
            }
        }
    }
}

// ---------------------------------------------------------------------------
// LayerNorm: one wave per row of 384
// ---------------------------------------------------------------------------
__global__ __launch_bounds__(64) void ln_kernel(
    const float* __restrict__ q, const float* __restrict__ w,
    const float* __restrict__ b, float* __restrict__ xout)
{
    const int n = blockIdx.x, lane = threadIdx.x;
    const float* row = q + (size_t)n * DIM;
    float v[6], s = 0.f, s2 = 0.f;
#pragma unroll
    for (int i = 0; i < 6; ++i) {
        v[i] = row[lane + i * 64];
        s += v[i]; s2 += v[i] * v[i];
    }
#pragma unroll
    for (int m = 32; m; m >>= 1) { s += __shfl_xor(s, m); s2 += __shfl_xor(s2, m); }
    float mu  = s * (1.f / DIM);
    float var = s2 * (1.f / DIM) - mu * mu;
    float rs  = rsqrtf(var + 1e-5f);
#pragma unroll
    for (int i = 0; i < 6; ++i) {
        int d = lane + i * 64;
        xout[(size_t)n * DIM + d] = (v[i] - mu) * rs * w[d] + b[d];
    }
}

// ---------------------------------------------------------------------------
// Pre-rotate the k-half of the kv map in place. One thread per (row, head):
// 6 x bf16x8 vector loads, 24 sincos (table freqs, no powf), vector stores.
// ---------------------------------------------------------------------------
__global__ __launch_bounds__(256) void rope_k_kernel(bf16_t* __restrict__ kvm, int Mkv)
{
    const float FS[8] = {1.0f, 0.7498942093f, 0.5623413252f, 0.4216965034f,
                         0.3162277660f, 0.2371373706f, 0.1778279410f, 0.1333521432f};
    const float FL[8] = {1.0f, 1.3335214322f, 1.7782794100f, 2.3713737057f,
                         3.1622776602f, 4.2169650343f, 5.6234132519f, 7.4989420933f};
    int t = blockIdx.x * 256 + threadIdx.x;
    if (t >= Mkv * NHEAD) return;
    int row = t >> 3, h = t & 7;

    int rr = row % TOTAL;
    int l, i, j;
    if (rr < 4096)      { l = 0; i = rr >> 6;               j = rr & 63; }
    else if (rr < 5120) { l = 1; int u = rr - 4096; i = u >> 5; j = u & 31; }
    else if (rr < 5376) { l = 2; int u = rr - 5120; i = u >> 4; j = u & 15; }
    else                { l = 3; int u = rr - 5376; i = u >> 3; j = u & 7;  }
    const float ci = (float)i, cj = (float)j, cl = (float)l;

    bf16_t* base = kvm + (size_t)row * (2 * DIM) + h * HDIM;
    bf16x8 xa[3], xb[3];
#pragma unroll
    for (int k = 0; k < 3; ++k) {
        xa[k] = *(const bf16x8*)(base + 8 * k);
        xb[k] = *(const bf16x8*)(base + HALFD + 8 * k);
    }
#pragma unroll
    for (int d = 0; d < HALFD; ++d) {
        float coord = (d < 8) ? ci : (d < 16) ? cj : cl;
        float freq  = (d < 8) ? FS[d] : (d < 16) ? FS[d - 8] : FL[d - 16];
        float s, c;
        __sincosf(coord * freq, &s, &c);
        float x1 = (float)xa[d >> 3][d & 7];
        float x2 = (float)xb[d >> 3][d & 7];
        xa[d >> 3][d & 7] = (bf16_t)(x1 * c - x2 * s);
        xb[d >> 3][d & 7] = (bf16_t)(x1 * s + x2 * c);
    }
#pragma unroll
    for (int k = 0; k < 3; ++k) {
        *(bf16x8*)(base + 8 * k)         = xa[k];
        *(bf16x8*)(base + HALFD + 8 * k) = xb[k];
    }
}

// ---------------------------------------------------------------------------
// Attention: one block (256 threads) per query; k already RoPE'd in kvm.
// ---------------------------------------------------------------------------
__global__ __launch_bounds__(256) void attn_kernel(
    const float* __restrict__ qproj,   // (N,384) pre-RoPE
    const int*   __restrict__ pos,     // (N,4) b,i,j,l
    const bf16_t* __restrict__ kvm,    // (B*total, 768) bf16, k pre-rotated
    float* __restrict__ attn_out)      // (N,384)
{
    const float FS[8] = {1.0f, 0.7498942093f, 0.5623413252f, 0.4216965034f,
                         0.3162277660f, 0.2371373706f, 0.1778279410f, 0.1333521432f};
    const float FL[8] = {1.0f, 1.3335214322f, 1.7782794100f, 2.3713737057f,
                         3.1622776602f, 4.2169650343f, 5.6234132519f, 7.4989420933f};
    __shared__ float qs[DIM];
    __shared__ float sc[NHEAD * NKEY];
    __shared__ int   flatL[NKEY], validL[NKEY];

    const int n = blockIdx.x, tid = threadIdx.x;
    const int b  = pos[n * 4 + 0];
    const int qi = pos[n * 4 + 1];
    const int qj = pos[n * 4 + 2];
    const int ql = pos[n * 4 + 3];

    const float Hq = (float)(64 >> ql);   // H == W at every level

    // q RoPE -> qs
    if (tid < NHEAD * HALFD) {
        int h = tid / HALFD, d = tid - h * HALFD;
        float coord, freq;
        if (d < 8)       { coord = (float)qi; freq = FS[d]; }
        else if (d < 16) { coord = (float)qj; freq = FS[d - 8]; }
        else             { coord = (float)ql; freq = FL[d - 16]; }
        float s, c;
        __sincosf(coord * freq, &s, &c);
        float x1 = qproj[(size_t)n * DIM + h * HDIM + d];
        float x2 = qproj[(size_t)n * DIM + h * HDIM + HALFD + d];
        qs[h * HDIM + d]         = x1 * c - x2 * s;
        qs[h * HDIM + HALFD + d] = x1 * s + x2 * c;
    }

    // per-key geometry
    if (tid < NKEY) {
        int kk = tid;
        int l = kk / 49;
        int rem = kk - l * 49;
        int a = rem / 7, bb = rem - a * 7;
        int Hl = 64 >> l;
        int off = (l == 0) ? 0 : (l == 1) ? 4096 : (l == 2) ? 5120 : 5376;
        float cif = floorf(((float)qi + 0.5f) * (float)Hl / Hq);
        float cjf = floorf(((float)qj + 0.5f) * (float)Hl / Hq);
        int ii = (int)cif + (a - 3);
        int jj = (int)cjf + (bb - 3);
        int vi = (ii >= 0) && (ii < Hl);
        int vj = (jj >= 0) && (jj < Hl);
        int iic = min(max(ii, 0), Hl - 1);
        int jjc = min(max(jj, 0), Hl - 1);
        flatL[kk]  = off + iic * Hl + jjc;
        validL[kk] = vi && vj;
    }
    __syncthreads();

    const size_t bbase = (size_t)b * TOTAL;

    // scores: 8 heads x 196 keys (k is pre-rotated)
    for (int idx = tid; idx < NHEAD * NKEY; idx += 256) {
        int h = idx / NKEY, kk = idx - h * NKEY;
        const bf16_t* krow = kvm + (bbase + (size_t)flatL[kk]) * (2 * DIM) + h * HDIM;
        bf16x8 kv[6];
#pragma unroll
        for (int i = 0; i < 6; ++i) kv[i] = *(const bf16x8*)(krow + i * 8);
        float dot = 0.f;
#pragma unroll
        for (int i = 0; i < 6; ++i)
#pragma unroll
            for (int e = 0; e < 8; ++e)
                dot += (float)kv[i][e] * qs[h * HDIM + i * 8 + e];
        float score = dot * 0.14433756729740643f;  // 1/sqrt(48)
        if (!validL[kk]) score = -1e9f;
        sc[h * NKEY + kk] = score;
    }
    __syncthreads();

    // softmax: head h handled by threads [h*32, h*32+32)
    {
        int h = tid >> 5, lg = tid & 31;
        float mx = -1e30f;
        for (int j = lg; j < NKEY; j += 32) mx = fmaxf(mx, sc[h * NKEY + j]);
#pragma unroll
        for (int m = 16; m; m >>= 1) mx = fmaxf(mx, __shfl_xor(mx, m));
        float sum = 0.f;
        for (int j = lg; j < NKEY; j += 32) {
            float e = __expf(sc[h * NKEY + j] - mx);
            sc[h * NKEY + j] = e; sum += e;
        }
#pragma unroll
        for (int m = 16; m; m >>= 1) sum += __shfl_xor(sum, m);
        float inv = 1.f / sum;
        for (int j = lg; j < NKEY; j += 32) sc[h * NKEY + j] *= inv;
    }
    __syncthreads();

    // V accumulation: 192 threads x 2 dims
    if (tid < 192) {
        int h = tid / 24;
        float a0 = 0.f, a1 = 0.f;
#pragma unroll 4
        for (int kk = 0; kk < NKEY; ++kk) {
            float w = sc[h * NKEY + kk];
            const bf16_t* vr = kvm + (bbase + (size_t)flatL[kk]) * (2 * DIM) + DIM + 2 * tid;
            bf16x2 vv = *(const bf16x2*)vr;
            a0 += w * (float)vv[0];
            a1 += w * (float)vv[1];
        }
        attn_out[(size_t)n * DIM + 2 * tid]     = a0;
        attn_out[(size_t)n * DIM + 2 * tid + 1] = a1;
    }
}

// ---------------------------------------------------------------------------
extern "C" void kernel_launch(void* const* d_in, const int* in_sizes, int n_in,
                              void* d_out, int out_size, void* d_ws, size_t ws_size,
                              hipStream_t stream)
{
    const float* query  = (const float*)d_in[0];
    const int*   pos    = (const int*)d_in[1];
    const float* fmaps  = (const float*)d_in[3];
    const float* nw     = (const float*)d_in[5];
    const float* nb     = (const float*)d_in[6];
    const float* wq     = (const float*)d_in[7];
    const float* wkv    = (const float*)d_in[8];
    const float* wout   = (const float*)d_in[9];
    float* out = (float*)d_out;

    const int Mkv = in_sizes[3] / DIM;  // B*total = 21760

    char* w = (char*)d_ws;
    float* x_ln   = (float*)w;  w += ((size_t)NQ * DIM * 4 + 255) / 256 * 256;
    float* qproj  = (float*)w;  w += ((size_t)NQ * DIM * 4 + 255) / 256 * 256;
    float* attn_o = (float*)w;  w += ((size_t)NQ * DIM * 4 + 255) / 256 * 256;
    bf16_t* kvm   = (bf16_t*)w; // Mkv * 768 * 2 bytes

    ln_kernel<<<NQ, 64, 0, stream>>>(query, nw, nb, x_ln);
    gemm_nt<0, 64><<<dim3(DIM / 64, NQ / 64), 256, 0, stream>>>(
        x_ln, wq, (void*)qproj, nullptr, NQ, DIM, DIM);
    gemm_nt<2, 128><<<dim3((2 * DIM) / 128, Mkv / 128), 256, 0, stream>>>(
        fmaps, wkv, (void*)kvm, nullptr, Mkv, 2 * DIM, DIM);
    {
        int tasks = Mkv * NHEAD;
        rope_k_kernel<<<(tasks + 255) / 256, 256, 0, stream>>>(kvm, Mkv);
    }
    attn_kernel<<<NQ, 256, 0, stream>>>(qproj, pos, kvm, attn_o);
    gemm_nt<1, 64><<<dim3(DIM / 64, NQ / 64), 256, 0, stream>>>(
        attn_o, wout, (void*)out, query, NQ, DIM, DIM);
}

// Round 4
// 115.778 us; speedup vs baseline: 1.5325x; 1.0106x over previous
//
#include <hip/hip_runtime.h>
#include <hip/hip_bf16.h>

typedef __bf16 bf16_t;
typedef __attribute__((ext_vector_type(4))) float f32x4;
typedef __attribute__((ext_vector_type(8))) __bf16 bf16x8;
typedef __attribute__((ext_vector_type(4))) __bf16 bf16x4;
typedef __attribute__((ext_vector_type(2))) __bf16 bf16x2;

#define NQ    1024
#define DIM   384
#define NHEAD 8
#define HDIM  48
#define HALFD 24
#define NKEY  196
#define TOTAL 5440   // 64*64 + 32*32 + 16*16 + 8*8

typedef __attribute__((address_space(1))) void gas_void;
typedef __attribute__((address_space(3))) void las_void;
__device__ __forceinline__ void gload16(const void* g, void* l) {
    __builtin_amdgcn_global_load_lds((gas_void*)g, (las_void*)l, 16, 0, 0);
}

// ---------------------------------------------------------------------------
// sincos tables: tabS[c*8+f] = (cos, sin)(c * 10^(-f/8)) for c in [0,64)
//                tabL[l*8+f] = (cos, sin)(l * 10^(+f/8)) for l in [0,4)
// ---------------------------------------------------------------------------
__global__ void init_tab_kernel(float2* __restrict__ tabS, float2* __restrict__ tabL)
{
    int t = threadIdx.x;
    if (t < 512) {
        int i = t >> 3, f = t & 7;
        float fr = powf(10.f, -(float)f / 8.f);
        float s, c; sincosf((float)i * fr, &s, &c);
        tabS[t] = make_float2(c, s);
    } else if (t < 544) {
        int u = t - 512; int l = u >> 3, f = u & 7;
        float fr = powf(10.f, (float)f / 8.f);
        float s, c; sincosf((float)l * fr, &s, &c);
        tabL[u] = make_float2(c, s);
    }
}

// ---------------------------------------------------------------------------
// fp32 -> bf16 conversion, 4 elems/thread
// ---------------------------------------------------------------------------
__global__ __launch_bounds__(256) void cvt4_kernel(
    const float* __restrict__ src, bf16_t* __restrict__ dst, int n4)
{
    int i = blockIdx.x * 256 + threadIdx.x;
    if (i < n4) {
        float4 v = ((const float4*)src)[i];
        bf16x4 o = { (bf16_t)v.x, (bf16_t)v.y, (bf16_t)v.z, (bf16_t)v.w };
        ((bf16x4*)dst)[i] = o;
    }
}

// ---------------------------------------------------------------------------
// bf16 NT GEMM: C[M,N] = A[M,K] * B[N,K]^T, MFMA 16x16x32, BK=64.
// Staging via global_load_lds (16B) with XOR-swizzled SOURCE (linear LDS dest)
// so ds_read_b128 of a column-slice is ~2-way-conflict-free (T2/m201 pattern).
// EPI: 0 = fp32 C, 1 = fp32 C + resid, 2 = bf16 C.  BT = 128 or 64.
// Bijective XCD swizzle (m204) for L2 reuse.
// ---------------------------------------------------------------------------
template<int EPI, int BT>
__global__ __launch_bounds__(256) void gemm_bf16(
    const bf16_t* __restrict__ A, const bf16_t* __restrict__ Bw,
    void* __restrict__ Cp, const float* __restrict__ resid,
    int M, int Nout, int K)
{
    constexpr int FRG = BT / 32;   // 16x16 fragments per wave dim
    constexpr int WT  = BT / 2;    // wave tile
    __shared__ bf16_t As[BT * 64];
    __shared__ bf16_t Bs[BT * 64];
    const int tid = threadIdx.x;

    const int bid = blockIdx.y * gridDim.x + blockIdx.x;
    const int nwg = gridDim.x * gridDim.y;
    const int qq = nwg >> 3, rr8 = nwg & 7;
    const int xcd = bid & 7, loc = bid >> 3;
    const int swz = (xcd < rr8 ? xcd * (qq + 1) : rr8 * (qq + 1) + (xcd - rr8) * qq) + loc;
    const int bm = swz / gridDim.x, bn = swz % gridDim.x;

    const int wave = tid >> 6, lane = tid & 63;
    const int wr   = wave >> 1, wc = wave & 1;
    const int fr   = lane & 15, g = lane >> 4;

    f32x4 acc[FRG][FRG];
#pragma unroll
    for (int i = 0; i < FRG; ++i)
#pragma unroll
        for (int j = 0; j < FRG; ++j) acc[i][j] = (f32x4){0.f, 0.f, 0.f, 0.f};

    const bf16_t* Ab = A  + (size_t)bm * BT * K;
    const bf16_t* Bb = Bw + (size_t)bn * BT * K;

    for (int kt = 0; kt < K; kt += 64) {
        __syncthreads();
#pragma unroll
        for (int it = 0; it < BT / 32; ++it) {
            int chunk = it * 256 + wave * 64 + lane;   // 16B chunk id, lane-contig per wave
            int row = chunk >> 3, c8 = chunk & 7;
            int sc8 = c8 ^ (row & 7);                  // inverse-swizzled source column
            gload16(Ab + (size_t)row * K + kt + sc8 * 8, As + chunk * 8);
            gload16(Bb + (size_t)row * K + kt + sc8 * 8, Bs + chunk * 8);
        }
        __syncthreads();
#pragma unroll
        for (int kk = 0; kk < 2; ++kk) {
            bf16x8 af[FRG], bfr[FRG];
#pragma unroll
            for (int mi = 0; mi < FRG; ++mi) {
                int row = wr * WT + mi * 16 + fr;
                int c = (kk * 4 + g) ^ (row & 7);      // swizzled read
                af[mi] = *(const bf16x8*)(As + row * 64 + c * 8);
            }
#pragma unroll
            for (int ni = 0; ni < FRG; ++ni) {
                int row = wc * WT + ni * 16 + fr;
                int c = (kk * 4 + g) ^ (row & 7);
                bfr[ni] = *(const bf16x8*)(Bs + row * 64 + c * 8);
            }
#pragma unroll
            for (int mi = 0; mi < FRG; ++mi)
#pragma unroll
                for (int ni = 0; ni < FRG; ++ni)
                    acc[mi][ni] = __builtin_amdgcn_mfma_f32_16x16x32_bf16(
                        af[mi], bfr[ni], acc[mi][ni], 0, 0, 0);
        }
    }

    const int r0 = g << 2;
#pragma unroll
    for (int mi = 0; mi < FRG; ++mi) {
#pragma unroll
        for (int ni = 0; ni < FRG; ++ni) {
#pragma unroll
            for (int e = 0; e < 4; ++e) {
                int row = bm * BT + wr * WT + mi * 16 + r0 + e;
                int col = bn * BT + wc * WT + ni * 16 + fr;
                float v = acc[mi][ni][e];
                if (EPI == 2) {
                    ((bf16_t*)Cp)[(size_t)row * Nout + col] = (bf16_t)v;
                } else {
                    if (EPI == 1) v += resid[(size_t)row * Nout + col];
                    ((float*)Cp)[(size_t)row * Nout + col] = v;
                }
            }
        }
    }
}

// ---------------------------------------------------------------------------
// LayerNorm: one wave per row of 384, bf16 output
// ---------------------------------------------------------------------------
__global__ __launch_bounds__(64) void ln_kernel(
    const float* __restrict__ q, const float* __restrict__ w,
    const float* __restrict__ b, bf16_t* __restrict__ xout)
{
    const int n = blockIdx.x, lane = threadIdx.x;
    const float* row = q + (size_t)n * DIM;
    float v[6], s = 0.f, s2 = 0.f;
#pragma unroll
    for (int i = 0; i < 6; ++i) {
        v[i] = row[lane + i * 64];
        s += v[i]; s2 += v[i] * v[i];
    }
#pragma unroll
    for (int m = 32; m; m >>= 1) { s += __shfl_xor(s, m); s2 += __shfl_xor(s2, m); }
    float mu  = s * (1.f / DIM);
    float var = s2 * (1.f / DIM) - mu * mu;
    float rs  = rsqrtf(var + 1e-5f);
#pragma unroll
    for (int i = 0; i < 6; ++i) {
        int d = lane + i * 64;
        xout[(size_t)n * DIM + d] = (bf16_t)((v[i] - mu) * rs * w[d] + b[d]);
    }
}

// ---------------------------------------------------------------------------
// Pre-rotate the k-half of the kv map in place, sincos from tables.
// One thread per (row, head).
// ---------------------------------------------------------------------------
__global__ __launch_bounds__(256) void rope_k_kernel(
    bf16_t* __restrict__ kvm, const float2* __restrict__ tabS,
    const float2* __restrict__ tabL, int Mkv)
{
    int t = blockIdx.x * 256 + threadIdx.x;
    if (t >= Mkv * NHEAD) return;
    int row = t >> 3, h = t & 7;

    int rr = row % TOTAL;
    int l, i, j;
    if (rr < 4096)      { l = 0; i = rr >> 6;               j = rr & 63; }
    else if (rr < 5120) { l = 1; int u = rr - 4096; i = u >> 5; j = u & 31; }
    else if (rr < 5376) { l = 2; int u = rr - 5120; i = u >> 4; j = u & 15; }
    else                { l = 3; int u = rr - 5376; i = u >> 3; j = u & 7;  }

    bf16_t* base = kvm + (size_t)row * (2 * DIM) + h * HDIM;
    bf16x8 xa[3], xb[3];
#pragma unroll
    for (int k = 0; k < 3; ++k) {
        xa[k] = *(const bf16x8*)(base + 8 * k);
        xb[k] = *(const bf16x8*)(base + HALFD + 8 * k);
    }
#pragma unroll
    for (int d = 0; d < HALFD; ++d) {
        float2 cs = (d < 8) ? tabS[i * 8 + d]
                  : (d < 16) ? tabS[j * 8 + (d - 8)]
                             : tabL[l * 8 + (d - 16)];
        float x1 = (float)xa[d >> 3][d & 7];
        float x2 = (float)xb[d >> 3][d & 7];
        xa[d >> 3][d & 7] = (bf16_t)(x1 * cs.x - x2 * cs.y);
        xb[d >> 3][d & 7] = (bf16_t)(x1 * cs.y + x2 * cs.x);
    }
#pragma unroll
    for (int k = 0; k < 3; ++k) {
        *(bf16x8*)(base + 8 * k)         = xa[k];
        *(bf16x8*)(base + HALFD + 8 * k) = xb[k];
    }
}

// ---------------------------------------------------------------------------
// Attention: one block (256 threads) per query; k pre-rotated; bf16 output.
// ---------------------------------------------------------------------------
__global__ __launch_bounds__(256) void attn_kernel(
    const float* __restrict__ qproj,   // (N,384) pre-RoPE fp32
    const int*   __restrict__ pos,     // (N,4) b,i,j,l
    const bf16_t* __restrict__ kvm,    // (B*total, 768) bf16, k pre-rotated
    const float2* __restrict__ tabS, const float2* __restrict__ tabL,
    bf16_t* __restrict__ attn_out)     // (N,384) bf16
{
    __shared__ float qs[DIM];
    __shared__ float sc[NHEAD * NKEY];
    __shared__ int   flatL[NKEY], validL[NKEY];

    const int n = blockIdx.x, tid = threadIdx.x;
    const int b  = pos[n * 4 + 0];
    const int qi = pos[n * 4 + 1];
    const int qj = pos[n * 4 + 2];
    const int ql = pos[n * 4 + 3];

    const float Hq = (float)(64 >> ql);   // H == W at every level

    // q RoPE -> qs
    if (tid < NHEAD * HALFD) {
        int h = tid / HALFD, d = tid - h * HALFD;
        float2 cs = (d < 8) ? tabS[qi * 8 + d]
                  : (d < 16) ? tabS[qj * 8 + (d - 8)]
                             : tabL[ql * 8 + (d - 16)];
        float x1 = qproj[(size_t)n * DIM + h * HDIM + d];
        float x2 = qproj[(size_t)n * DIM + h * HDIM + HALFD + d];
        qs[h * HDIM + d]         = x1 * cs.x - x2 * cs.y;
        qs[h * HDIM + HALFD + d] = x1 * cs.y + x2 * cs.x;
    }

    // per-key geometry
    if (tid < NKEY) {
        int kk = tid;
        int l = kk / 49;
        int rem = kk - l * 49;
        int a = rem / 7, bb = rem - a * 7;
        int Hl = 64 >> l;
        int off = (l == 0) ? 0 : (l == 1) ? 4096 : (l == 2) ? 5120 : 5376;
        float cif = floorf(((float)qi + 0.5f) * (float)Hl / Hq);
        float cjf = floorf(((float)qj + 0.5f) * (float)Hl / Hq);
        int ii = (int)cif + (a - 3);
        int jj = (int)cjf + (bb - 3);
        int vi = (ii >= 0) && (ii < Hl);
        int vj = (jj >= 0) && (jj < Hl);
        int iic = min(max(ii, 0), Hl - 1);
        int jjc = min(max(jj, 0), Hl - 1);
        flatL[kk]  = off + iic * Hl + jjc;
        validL[kk] = vi && vj;
    }
    __syncthreads();

    const size_t bbase = (size_t)b * TOTAL;

    // scores: 8 heads x 196 keys
    for (int idx = tid; idx < NHEAD * NKEY; idx += 256) {
        int h = idx / NKEY, kk = idx - h * NKEY;
        const bf16_t* krow = kvm + (bbase + (size_t)flatL[kk]) * (2 * DIM) + h * HDIM;
        bf16x8 kv[6];
#pragma unroll
        for (int i = 0; i < 6; ++i) kv[i] = *(const bf16x8*)(krow + i * 8);
        float dot = 0.f;
#pragma unroll
        for (int i = 0; i < 6; ++i)
#pragma unroll
            for (int e = 0; e < 8; ++e)
                dot += (float)kv[i][e] * qs[h * HDIM + i * 8 + e];
        float score = dot * 0.14433756729740643f;  // 1/sqrt(48)
        if (!validL[kk]) score = -1e9f;
        sc[h * NKEY + kk] = score;
    }
    __syncthreads();

    // softmax: head h handled by threads [h*32, h*32+32)
    {
        int h = tid >> 5, lg = tid & 31;
        float mx = -1e30f;
        for (int j = lg; j < NKEY; j += 32) mx = fmaxf(mx, sc[h * NKEY + j]);
#pragma unroll
        for (int m = 16; m; m >>= 1) mx = fmaxf(mx, __shfl_xor(mx, m));
        float sum = 0.f;
        for (int j = lg; j < NKEY; j += 32) {
            float e = __expf(sc[h * NKEY + j] - mx);
            sc[h * NKEY + j] = e; sum += e;
        }
#pragma unroll
        for (int m = 16; m; m >>= 1) sum += __shfl_xor(sum, m);
        float inv = 1.f / sum;
        for (int j = lg; j < NKEY; j += 32) sc[h * NKEY + j] *= inv;
    }
    __syncthreads();

    // V accumulation: 192 threads x 2 dims
    if (tid < 192) {
        int h = tid / 24;
        float a0 = 0.f, a1 = 0.f;
#pragma unroll 4
        for (int kk = 0; kk < NKEY; ++kk) {
            float w = sc[h * NKEY + kk];
            const bf16_t* vr = kvm + (bbase + (size_t)flatL[kk]) * (2 * DIM) + DIM + 2 * tid;
            bf16x2 vv = *(const bf16x2*)vr;
            a0 += w * (float)vv[0];
            a1 += w * (float)vv[1];
        }
        bf16x2 o = { (bf16_t)a0, (bf16_t)a1 };
        *(bf16x2*)(attn_out + (size_t)n * DIM + 2 * tid) = o;
    }
}

// ---------------------------------------------------------------------------
extern "C" void kernel_launch(void* const* d_in, const int* in_sizes, int n_in,
                              void* d_out, int out_size, void* d_ws, size_t ws_size,
                              hipStream_t stream)
{
    const float* query  = (const float*)d_in[0];
    const int*   pos    = (const int*)d_in[1];
    const float* fmaps  = (const float*)d_in[3];
    const float* nw     = (const float*)d_in[5];
    const float* nb     = (const float*)d_in[6];
    const float* wq     = (const float*)d_in[7];
    const float* wkv    = (const float*)d_in[8];
    const float* wout   = (const float*)d_in[9];
    float* out = (float*)d_out;

    const int Mkv = in_sizes[3] / DIM;  // B*total = 21760

    char* w = (char*)d_ws;
    auto alloc = [&](size_t bytes) { char* p = w; w += (bytes + 255) & ~(size_t)255; return p; };
    bf16_t* x_ln    = (bf16_t*)alloc((size_t)NQ * DIM * 2);
    float*  qproj   = (float*) alloc((size_t)NQ * DIM * 4);
    bf16_t* attn_o  = (bf16_t*)alloc((size_t)NQ * DIM * 2);
    bf16_t* kvm     = (bf16_t*)alloc((size_t)Mkv * 2 * DIM * 2);
    bf16_t* fm_bf   = (bf16_t*)alloc((size_t)Mkv * DIM * 2);
    bf16_t* wq_bf   = (bf16_t*)alloc((size_t)DIM * DIM * 2);
    bf16_t* wkv_bf  = (bf16_t*)alloc((size_t)2 * DIM * DIM * 2);
    bf16_t* wout_bf = (bf16_t*)alloc((size_t)DIM * DIM * 2);
    float2* tabS    = (float2*)alloc(512 * 8);
    float2* tabL    = (float2*)alloc(32 * 8);

    init_tab_kernel<<<1, 576, 0, stream>>>(tabS, tabL);
    {
        int n4 = Mkv * DIM / 4;
        cvt4_kernel<<<(n4 + 255) / 256, 256, 0, stream>>>(fmaps, fm_bf, n4);
        int nw4 = DIM * DIM / 4;
        cvt4_kernel<<<(nw4 + 255) / 256, 256, 0, stream>>>(wq, wq_bf, nw4);
        cvt4_kernel<<<(2 * nw4 + 255) / 256, 256, 0, stream>>>(wkv, wkv_bf, 2 * nw4);
        cvt4_kernel<<<(nw4 + 255) / 256, 256, 0, stream>>>(wout, wout_bf, nw4);
    }
    ln_kernel<<<NQ, 64, 0, stream>>>(query, nw, nb, x_ln);
    gemm_bf16<0, 64><<<dim3(DIM / 64, NQ / 64), 256, 0, stream>>>(
        x_ln, wq_bf, (void*)qproj, nullptr, NQ, DIM, DIM);
    gemm_bf16<2, 128><<<dim3((2 * DIM) / 128, Mkv / 128), 256, 0, stream>>>(
        fm_bf, wkv_bf, (void*)kvm, nullptr, Mkv, 2 * DIM, DIM);
    rope_k_kernel<<<(Mkv * NHEAD + 255) / 256, 256, 0, stream>>>(kvm, tabS, tabL, Mkv);
    attn_kernel<<<NQ, 256, 0, stream>>>(qproj, pos, kvm, tabS, tabL, attn_o);
    gemm_bf16<1, 64><<<dim3(DIM / 64, NQ / 64), 256, 0, stream>>>(
        attn_o, wout_bf, (void*)out, query, NQ, DIM, DIM);
}